// Round 1
// baseline (967.659 us; speedup 1.0000x reference)
//
#include <hip/hip_runtime.h>

constexpr int N    = 8192;
constexpr int NPG  = 512;   // nodes per graph
constexpr int NG   = 16;
constexpr int KNN  = 80;
constexpr int F0   = 6;
constexpr int HID  = 128;
constexpr int H6   = 768;

__device__ __forceinline__ float leaky(float v) { return v > 0.0f ? v : 0.01f * v; }

// ---------------------------------------------------------------------------
// KNN: one workgroup per target node. Load the graph's 512 positions to LDS,
// compute d2 row, bitonic-sort (d2, idx) as packed u64 keys, emit first 80.
// Key mapping is the standard order-preserving float->uint transform, so
// ordering is (d2 asc, idx asc) == jax.lax.top_k(-d2) tie semantics.
// ---------------------------------------------------------------------------
__global__ __launch_bounds__(256) void knn_kernel(const float* __restrict__ x,
                                                  int* __restrict__ nbr) {
    const int t    = blockIdx.x;          // target node
    const int base = (t >> 9) << 9;       // graph start
    const int tid  = threadIdx.x;

    __shared__ float px[512], py[512], pz[512], pw[512];
    __shared__ unsigned long long key[512];

    for (int j = tid; j < 512; j += 256) {
        const float* row = x + (size_t)(base + j) * F0;
        px[j] = row[0]; py[j] = row[1]; pz[j] = row[2]; pw[j] = row[3];
    }
    __syncthreads();

    const int tl = t - base;
    const float tx = px[tl], ty = py[tl], tz = pz[tl], tw = pw[tl];
    const float sqt = tx*tx + ty*ty + tz*tz + tw*tw;

    for (int j = tid; j < 512; j += 256) {
        const float jx = px[j], jy = py[j], jz = pz[j], jw = pw[j];
        const float sqj = jx*jx + jy*jy + jz*jz + jw*jw;
        const float dot = tx*jx + ty*jy + tz*jz + tw*jw;
        const float d2  = sqt + sqj - 2.0f * dot;
        unsigned u = __float_as_uint(d2);
        u = (u & 0x80000000u) ? ~u : (u | 0x80000000u);   // monotonic map
        if (j == tl) u = 0xFFFFFFFFu;                     // exclude self (max key)
        key[j] = ((unsigned long long)u << 32) | (unsigned)(base + j);
    }
    __syncthreads();

    // bitonic sort, 512 elems, 256 threads (2 elems/thread; pairs per rep are
    // disjoint halves, so no barrier needed between reps)
    for (int kk = 2; kk <= 512; kk <<= 1) {
        for (int jj = kk >> 1; jj > 0; jj >>= 1) {
            #pragma unroll
            for (int rep = 0; rep < 2; rep++) {
                const int i  = tid + rep * 256;
                const int ix = i ^ jj;
                if (ix > i) {
                    const unsigned long long a = key[i], b = key[ix];
                    const bool up = ((i & kk) == 0);
                    if ((a > b) == up) { key[i] = b; key[ix] = a; }
                }
            }
            __syncthreads();
        }
    }

    if (tid < KNN) nbr[t * KNN + tid] = (int)(key[tid] & 0xFFFFFFFFu);
}

// ---------------------------------------------------------------------------
// Propagation Y[t] = (1/80) * sum_{s in nbr(t)} H[s]
// ---------------------------------------------------------------------------
__global__ __launch_bounds__(256) void prop6(const float* __restrict__ hin,
                                             const int* __restrict__ nbr,
                                             float* __restrict__ hout) {
    const int t = blockIdx.x * 256 + threadIdx.x;
    if (t >= N) return;
    const int* nb = nbr + t * KNN;
    float a0=0.f,a1=0.f,a2=0.f,a3=0.f,a4=0.f,a5=0.f;
    for (int i = 0; i < KNN; i += 4) {
        const int4 s4 = *(const int4*)(nb + i);
        {   const float* r = hin + (size_t)s4.x * F0;
            a0+=r[0]; a1+=r[1]; a2+=r[2]; a3+=r[3]; a4+=r[4]; a5+=r[5]; }
        {   const float* r = hin + (size_t)s4.y * F0;
            a0+=r[0]; a1+=r[1]; a2+=r[2]; a3+=r[3]; a4+=r[4]; a5+=r[5]; }
        {   const float* r = hin + (size_t)s4.z * F0;
            a0+=r[0]; a1+=r[1]; a2+=r[2]; a3+=r[3]; a4+=r[4]; a5+=r[5]; }
        {   const float* r = hin + (size_t)s4.w * F0;
            a0+=r[0]; a1+=r[1]; a2+=r[2]; a3+=r[3]; a4+=r[4]; a5+=r[5]; }
    }
    const float inv = 1.0f / 80.0f;
    float* o = hout + (size_t)t * F0;
    o[0]=a0*inv; o[1]=a1*inv; o[2]=a2*inv; o[3]=a3*inv; o[4]=a4*inv; o[5]=a5*inv;
}

__global__ __launch_bounds__(256) void prop128(const float* __restrict__ hin,
                                               const int* __restrict__ nbr,
                                               float* __restrict__ hout) {
    const int lane = threadIdx.x & 31;          // 32 lanes cover 128 feats (float4)
    const int t    = blockIdx.x * 8 + (threadIdx.x >> 5);
    const int* nb  = nbr + t * KNN;
    float a0=0.f,a1=0.f,a2=0.f,a3=0.f;
    for (int i = 0; i < KNN; i += 4) {
        const int4 s4 = *(const int4*)(nb + i);
        const float4 v0 = *(const float4*)(hin + (size_t)s4.x * HID + lane * 4);
        const float4 v1 = *(const float4*)(hin + (size_t)s4.y * HID + lane * 4);
        const float4 v2 = *(const float4*)(hin + (size_t)s4.z * HID + lane * 4);
        const float4 v3 = *(const float4*)(hin + (size_t)s4.w * HID + lane * 4);
        a0 += v0.x + v1.x + v2.x + v3.x;
        a1 += v0.y + v1.y + v2.y + v3.y;
        a2 += v0.z + v1.z + v2.z + v3.z;
        a3 += v0.w + v1.w + v2.w + v3.w;
    }
    const float inv = 1.0f / 80.0f;
    float4 r; r.x=a0*inv; r.y=a1*inv; r.z=a2*inv; r.w=a3*inv;
    *(float4*)(hout + (size_t)t * HID + lane * 4) = r;
}

// ---------------------------------------------------------------------------
// Fused TAGConv combine: out = leaky(X@W0 + Y1@W1 + Y2@W2 + b)
// W layout (3, K, 128). Thread = output column; wg covers 32 rows.
// ---------------------------------------------------------------------------
template<int K>
__global__ __launch_bounds__(256) void combine_kernel(const float* __restrict__ X,
                                                      const float* __restrict__ Y1,
                                                      const float* __restrict__ Y2,
                                                      const float* __restrict__ W,
                                                      const float* __restrict__ bias,
                                                      float* __restrict__ out) {
    const int c    = threadIdx.x & 127;
    const int row0 = blockIdx.x * 32 + (threadIdx.x >> 7) * 16;
    const float* __restrict__ W0 = W;
    const float* __restrict__ W1 = W + K * HID;
    const float* __restrict__ W2 = W + 2 * K * HID;

    for (int rr = 0; rr < 16; rr += 4) {
        const int r = row0 + rr;
        float a0=0.f,a1=0.f,a2=0.f,a3=0.f;
        const float* x0 = X  + (size_t)r * K;
        const float* y1 = Y1 + (size_t)r * K;
        const float* y2 = Y2 + (size_t)r * K;
        #pragma unroll 4
        for (int k = 0; k < K; k++) {
            const float w = W0[k * HID + c];
            a0 += x0[k] * w; a1 += x0[K + k] * w;
            a2 += x0[2*K + k] * w; a3 += x0[3*K + k] * w;
        }
        #pragma unroll 4
        for (int k = 0; k < K; k++) {
            const float w = W1[k * HID + c];
            a0 += y1[k] * w; a1 += y1[K + k] * w;
            a2 += y1[2*K + k] * w; a3 += y1[3*K + k] * w;
        }
        #pragma unroll 4
        for (int k = 0; k < K; k++) {
            const float w = W2[k * HID + c];
            a0 += y2[k] * w; a1 += y2[K + k] * w;
            a2 += y2[2*K + k] * w; a3 += y2[3*K + k] * w;
        }
        const float bb = bias[c];
        out[(size_t)(r+0) * HID + c] = leaky(a0 + bb);
        out[(size_t)(r+1) * HID + c] = leaky(a1 + bb);
        out[(size_t)(r+2) * HID + c] = leaky(a2 + bb);
        out[(size_t)(r+3) * HID + c] = leaky(a3 + bb);
    }
}

// ---------------------------------------------------------------------------
// Per-graph mean+max pool of one conv output into g[:, conv*256 .. +256)
// ---------------------------------------------------------------------------
__global__ __launch_bounds__(256) void pool_kernel(const float* __restrict__ h,
                                                   float* __restrict__ g, int conv) {
    const int gr   = blockIdx.x;
    const int c    = threadIdx.x & 127;
    const int half = threadIdx.x >> 7;
    const float* hb = h + (size_t)gr * NPG * HID;
    float sum = 0.0f, mx = -3.402823e38f;
    for (int n = half * 256; n < half * 256 + 256; n++) {
        const float v = hb[(size_t)n * HID + c];
        sum += v; mx = fmaxf(mx, v);
    }
    __shared__ float ssum[128], smx[128];
    if (half) { ssum[c] = sum; smx[c] = mx; }
    __syncthreads();
    if (!half) {
        sum += ssum[c];
        mx = fmaxf(mx, smx[c]);
        float* grow = g + (size_t)gr * H6 + conv * 256;
        grow[c]       = sum * (1.0f / 512.0f);
        grow[128 + c] = mx;
    }
}

__global__ void bn_kernel(float* __restrict__ g,
                          const float* __restrict__ gamma, const float* __restrict__ beta,
                          const float* __restrict__ mean,  const float* __restrict__ var) {
    const int i = blockIdx.x * 256 + threadIdx.x;
    if (i < NG * H6) {
        const int c = i % H6;
        g[i] = (g[i] - mean[c]) * (1.0f / sqrtf(var[c] + 1e-5f)) * gamma[c] + beta[c];
    }
}

// head layer: gout(16,768) = leaky(gin(16,768) @ W(768,768) + b)
__global__ __launch_bounds__(256) void lin_kernel(const float* __restrict__ gin,
                                                  const float* __restrict__ W,
                                                  const float* __restrict__ bias,
                                                  float* __restrict__ gout) {
    const int gid = blockIdx.x * 256 + threadIdx.x;   // 3072 threads
    const int c   = gid % H6;
    const int r0  = (gid / H6) * 4;
    float a0=0.f,a1=0.f,a2=0.f,a3=0.f;
    const float* g0 = gin + (size_t)r0 * H6;
    #pragma unroll 4
    for (int k = 0; k < H6; k++) {
        const float w = W[(size_t)k * H6 + c];
        a0 += g0[k] * w;
        a1 += g0[H6 + k] * w;
        a2 += g0[2*H6 + k] * w;
        a3 += g0[3*H6 + k] * w;
    }
    const float bb = bias[c];
    gout[(size_t)(r0+0)*H6 + c] = leaky(a0 + bb);
    gout[(size_t)(r0+1)*H6 + c] = leaky(a1 + bb);
    gout[(size_t)(r0+2)*H6 + c] = leaky(a2 + bb);
    gout[(size_t)(r0+3)*H6 + c] = leaky(a3 + bb);
}

__global__ void out_kernel(const float* __restrict__ gin,
                           const float* __restrict__ W,
                           const float* __restrict__ bias,
                           float* __restrict__ out) {
    const int tid = threadIdx.x;
    if (tid >= 48) return;
    const int r = tid / 3, c = tid % 3;
    float acc = bias[c];
    for (int k = 0; k < H6; k++) acc += gin[(size_t)r * H6 + k] * W[(size_t)k * 3 + c];
    out[r * 3 + c] = acc;
}

// ---------------------------------------------------------------------------
extern "C" void kernel_launch(void* const* d_in, const int* in_sizes, int n_in,
                              void* d_out, int out_size, void* d_ws, size_t ws_size,
                              hipStream_t stream) {
    const float* x        = (const float*)d_in[0];
    // d_in[1] = batch: contiguous 512-node blocks by construction; unused.
    const float* conv1_w  = (const float*)d_in[2];
    const float* conv1_b  = (const float*)d_in[3];
    const float* conv2_w  = (const float*)d_in[4];
    const float* conv2_b  = (const float*)d_in[5];
    const float* conv3_w  = (const float*)d_in[6];
    const float* conv3_b  = (const float*)d_in[7];
    const float* bn_gamma = (const float*)d_in[8];
    const float* bn_beta  = (const float*)d_in[9];
    const float* bn_mean  = (const float*)d_in[10];
    const float* bn_var   = (const float*)d_in[11];
    const float* lin_w    = (const float*)d_in[12];
    const float* lin_b    = (const float*)d_in[13];
    const float* out_w    = (const float*)d_in[14];
    const float* out_b    = (const float*)d_in[15];

    char* ws = (char*)d_ws;
    size_t off = 0;
    auto alloc = [&](size_t bytes) {
        void* p = ws + off;
        off += (bytes + 255) & ~(size_t)255;
        return p;
    };
    int*   nbr = (int*)  alloc((size_t)N * KNN * 4);
    float* y6a = (float*)alloc((size_t)N * F0 * 4);
    float* y6b = (float*)alloc((size_t)N * F0 * 4);
    float* hA  = (float*)alloc((size_t)N * HID * 4);
    float* hB  = (float*)alloc((size_t)N * HID * 4);
    float* y1  = (float*)alloc((size_t)N * HID * 4);
    float* y2  = (float*)alloc((size_t)N * HID * 4);
    float* ga  = (float*)alloc((size_t)NG * H6 * 4);
    float* gb  = (float*)alloc((size_t)NG * H6 * 4);

    knn_kernel<<<N, 256, 0, stream>>>(x, nbr);

    // conv1 (K=6)
    prop6<<<N / 256, 256, 0, stream>>>(x, nbr, y6a);
    prop6<<<N / 256, 256, 0, stream>>>(y6a, nbr, y6b);
    combine_kernel<6><<<N / 32, 256, 0, stream>>>(x, y6a, y6b, conv1_w, conv1_b, hA);
    pool_kernel<<<NG, 256, 0, stream>>>(hA, ga, 0);

    // conv2 (K=128)
    prop128<<<N / 8, 256, 0, stream>>>(hA, nbr, y1);
    prop128<<<N / 8, 256, 0, stream>>>(y1, nbr, y2);
    combine_kernel<128><<<N / 32, 256, 0, stream>>>(hA, y1, y2, conv2_w, conv2_b, hB);
    pool_kernel<<<NG, 256, 0, stream>>>(hB, ga, 1);

    // conv3 (K=128)
    prop128<<<N / 8, 256, 0, stream>>>(hB, nbr, y1);
    prop128<<<N / 8, 256, 0, stream>>>(y1, nbr, y2);
    combine_kernel<128><<<N / 32, 256, 0, stream>>>(hB, y1, y2, conv3_w, conv3_b, hA);
    pool_kernel<<<NG, 256, 0, stream>>>(hA, ga, 2);

    // head
    bn_kernel<<<(NG * H6 + 255) / 256, 256, 0, stream>>>(ga, bn_gamma, bn_beta, bn_mean, bn_var);
    lin_kernel<<<12, 256, 0, stream>>>(ga, lin_w + 0 * H6 * H6, lin_b + 0 * H6, gb);
    lin_kernel<<<12, 256, 0, stream>>>(gb, lin_w + 1 * H6 * H6, lin_b + 1 * H6, ga);
    lin_kernel<<<12, 256, 0, stream>>>(ga, lin_w + 2 * H6 * H6, lin_b + 2 * H6, gb);
    lin_kernel<<<12, 256, 0, stream>>>(gb, lin_w + 3 * H6 * H6, lin_b + 3 * H6, ga);
    lin_kernel<<<12, 256, 0, stream>>>(ga, lin_w + 4 * H6 * H6, lin_b + 4 * H6, gb);
    out_kernel<<<1, 64, 0, stream>>>(gb, out_w, out_b, (float*)d_out);
}

// Round 2
// 570.504 us; speedup vs baseline: 1.6961x; 1.6961x over previous
//
#include <hip/hip_runtime.h>

constexpr int N    = 8192;
constexpr int NPG  = 512;   // nodes per graph
constexpr int NG   = 16;
constexpr int KNN  = 80;
constexpr int F0   = 6;
constexpr int HID  = 128;
constexpr int H6   = 768;

__device__ __forceinline__ float leaky(float v) { return v > 0.0f ? v : 0.01f * v; }

// ---------------------------------------------------------------------------
// KNN: one workgroup per target node. Load the graph's 512 positions to LDS,
// compute d2 row, bitonic-sort (d2, idx) as packed u64 keys, emit first 80.
// Order-preserving float->uint transform => (d2 asc, idx asc), matching
// jax.lax.top_k(-d2) tie semantics.
// ---------------------------------------------------------------------------
__global__ __launch_bounds__(256) void knn_kernel(const float* __restrict__ x,
                                                  int* __restrict__ nbr) {
    const int t    = blockIdx.x;          // target node
    const int base = (t >> 9) << 9;       // graph start
    const int tid  = threadIdx.x;

    __shared__ float px[512], py[512], pz[512], pw[512];
    __shared__ unsigned long long key[512];

    for (int j = tid; j < 512; j += 256) {
        const float* row = x + (size_t)(base + j) * F0;
        px[j] = row[0]; py[j] = row[1]; pz[j] = row[2]; pw[j] = row[3];
    }
    __syncthreads();

    const int tl = t - base;
    const float tx = px[tl], ty = py[tl], tz = pz[tl], tw = pw[tl];
    const float sqt = tx*tx + ty*ty + tz*tz + tw*tw;

    for (int j = tid; j < 512; j += 256) {
        const float jx = px[j], jy = py[j], jz = pz[j], jw = pw[j];
        const float sqj = jx*jx + jy*jy + jz*jz + jw*jw;
        const float dot = tx*jx + ty*jy + tz*jz + tw*jw;
        const float d2  = sqt + sqj - 2.0f * dot;
        unsigned u = __float_as_uint(d2);
        u = (u & 0x80000000u) ? ~u : (u | 0x80000000u);   // monotonic map
        if (j == tl) u = 0xFFFFFFFFu;                     // exclude self (max key)
        key[j] = ((unsigned long long)u << 32) | (unsigned)(base + j);
    }
    __syncthreads();

    for (int kk = 2; kk <= 512; kk <<= 1) {
        for (int jj = kk >> 1; jj > 0; jj >>= 1) {
            #pragma unroll
            for (int rep = 0; rep < 2; rep++) {
                const int i  = tid + rep * 256;
                const int ix = i ^ jj;
                if (ix > i) {
                    const unsigned long long a = key[i], b = key[ix];
                    const bool up = ((i & kk) == 0);
                    if ((a > b) == up) { key[i] = b; key[ix] = a; }
                }
            }
            __syncthreads();
        }
    }

    if (tid < KNN) nbr[t * KNN + tid] = (int)(key[tid] & 0xFFFFFFFFu);
}

// ---------------------------------------------------------------------------
// Propagation Y[t] = (1/80) * sum_{s in nbr(t)} H[s]
// ---------------------------------------------------------------------------
__global__ __launch_bounds__(256) void prop6(const float* __restrict__ hin,
                                             const int* __restrict__ nbr,
                                             float* __restrict__ hout) {
    const int t = blockIdx.x * 256 + threadIdx.x;
    if (t >= N) return;
    const int* nb = nbr + t * KNN;
    float a0=0.f,a1=0.f,a2=0.f,a3=0.f,a4=0.f,a5=0.f;
    for (int i = 0; i < KNN; i += 4) {
        const int4 s4 = *(const int4*)(nb + i);
        {   const float* r = hin + (size_t)s4.x * F0;
            a0+=r[0]; a1+=r[1]; a2+=r[2]; a3+=r[3]; a4+=r[4]; a5+=r[5]; }
        {   const float* r = hin + (size_t)s4.y * F0;
            a0+=r[0]; a1+=r[1]; a2+=r[2]; a3+=r[3]; a4+=r[4]; a5+=r[5]; }
        {   const float* r = hin + (size_t)s4.z * F0;
            a0+=r[0]; a1+=r[1]; a2+=r[2]; a3+=r[3]; a4+=r[4]; a5+=r[5]; }
        {   const float* r = hin + (size_t)s4.w * F0;
            a0+=r[0]; a1+=r[1]; a2+=r[2]; a3+=r[3]; a4+=r[4]; a5+=r[5]; }
    }
    const float inv = 1.0f / 80.0f;
    float* o = hout + (size_t)t * F0;
    o[0]=a0*inv; o[1]=a1*inv; o[2]=a2*inv; o[3]=a3*inv; o[4]=a4*inv; o[5]=a5*inv;
}

__global__ __launch_bounds__(256) void prop128(const float* __restrict__ hin,
                                               const int* __restrict__ nbr,
                                               float* __restrict__ hout) {
    const int lane = threadIdx.x & 31;          // 32 lanes cover 128 feats (float4)
    const int t    = blockIdx.x * 8 + (threadIdx.x >> 5);
    const int* nb  = nbr + t * KNN;
    float a0=0.f,a1=0.f,a2=0.f,a3=0.f;
    for (int i = 0; i < KNN; i += 8) {
        const int4 s4 = *(const int4*)(nb + i);
        const int4 s8 = *(const int4*)(nb + i + 4);
        const float4 v0 = *(const float4*)(hin + (size_t)s4.x * HID + lane * 4);
        const float4 v1 = *(const float4*)(hin + (size_t)s4.y * HID + lane * 4);
        const float4 v2 = *(const float4*)(hin + (size_t)s4.z * HID + lane * 4);
        const float4 v3 = *(const float4*)(hin + (size_t)s4.w * HID + lane * 4);
        const float4 v4 = *(const float4*)(hin + (size_t)s8.x * HID + lane * 4);
        const float4 v5 = *(const float4*)(hin + (size_t)s8.y * HID + lane * 4);
        const float4 v6 = *(const float4*)(hin + (size_t)s8.z * HID + lane * 4);
        const float4 v7 = *(const float4*)(hin + (size_t)s8.w * HID + lane * 4);
        a0 += (v0.x + v1.x) + (v2.x + v3.x) + (v4.x + v5.x) + (v6.x + v7.x);
        a1 += (v0.y + v1.y) + (v2.y + v3.y) + (v4.y + v5.y) + (v6.y + v7.y);
        a2 += (v0.z + v1.z) + (v2.z + v3.z) + (v4.z + v5.z) + (v6.z + v7.z);
        a3 += (v0.w + v1.w) + (v2.w + v3.w) + (v4.w + v5.w) + (v6.w + v7.w);
    }
    const float inv = 1.0f / 80.0f;
    float4 r; r.x=a0*inv; r.y=a1*inv; r.z=a2*inv; r.w=a3*inv;
    *(float4*)(hout + (size_t)t * HID + lane * 4) = r;
}

// ---------------------------------------------------------------------------
// Fused TAGConv combine as LDS-tiled GEMM:
//   out = leaky([X|Y1|Y2] @ [W0;W1;W2] + b), tile = 16 rows x 128 cols.
// 256 threads: thread = (col, row-half); 8 outputs/thread. Grid = 512 blocks
// -> 2 blocks/CU, 2 waves/SIMD. LDS tile reads are wave-broadcast (no bank
// conflicts); W reads coalesced 256B/wave from L2. 16 FMA per 2 W-loads.
// ---------------------------------------------------------------------------
template<int K>
__global__ __launch_bounds__(256) void combine_kernel(const float* __restrict__ X,
                                                      const float* __restrict__ Y1,
                                                      const float* __restrict__ Y2,
                                                      const float* __restrict__ W,
                                                      const float* __restrict__ bias,
                                                      float* __restrict__ out) {
    __shared__ float xs[3][16 * K];
    const int tid  = threadIdx.x;
    const int row0 = blockIdx.x * 16;

    {   // cooperative tile load: 16 consecutive rows are contiguous in memory
        const float* s0 = X  + (size_t)row0 * K;
        const float* s1 = Y1 + (size_t)row0 * K;
        const float* s2 = Y2 + (size_t)row0 * K;
        if constexpr ((K & 3) == 0) {
            constexpr int NV = 16 * K / 4;
            for (int i = tid; i < NV; i += 256) ((float4*)xs[0])[i] = ((const float4*)s0)[i];
            for (int i = tid; i < NV; i += 256) ((float4*)xs[1])[i] = ((const float4*)s1)[i];
            for (int i = tid; i < NV; i += 256) ((float4*)xs[2])[i] = ((const float4*)s2)[i];
        } else {
            for (int i = tid; i < 16 * K; i += 256) xs[0][i] = s0[i];
            for (int i = tid; i < 16 * K; i += 256) xs[1][i] = s1[i];
            for (int i = tid; i < 16 * K; i += 256) xs[2][i] = s2[i];
        }
    }
    __syncthreads();

    const int c  = tid & 127;
    const int r0 = (tid >> 7) * 8;      // 0 or 8

    float acc[8];
    #pragma unroll
    for (int r = 0; r < 8; r++) acc[r] = 0.0f;

    #pragma unroll
    for (int s = 0; s < 3; s++) {
        const float* __restrict__ Ws   = W + (size_t)s * K * HID;
        const float* __restrict__ xseg = xs[s] + r0 * K;
        for (int k = 0; k < K; k += 2) {
            const float w0 = Ws[(size_t)k * HID + c];
            const float w1 = Ws[(size_t)(k + 1) * HID + c];
            #pragma unroll
            for (int r = 0; r < 8; r++)
                acc[r] += xseg[r * K + k] * w0 + xseg[r * K + k + 1] * w1;
        }
    }

    const float bb = bias[c];
    #pragma unroll
    for (int r = 0; r < 8; r++)
        out[(size_t)(row0 + r0 + r) * HID + c] = leaky(acc[r] + bb);
}

// ---------------------------------------------------------------------------
// Per-graph mean+max pool of one conv output into g[:, conv*256 .. +256)
// ---------------------------------------------------------------------------
__global__ __launch_bounds__(256) void pool_kernel(const float* __restrict__ h,
                                                   float* __restrict__ g, int conv) {
    const int gr   = blockIdx.x;
    const int c    = threadIdx.x & 127;
    const int half = threadIdx.x >> 7;
    const float* hb = h + (size_t)gr * NPG * HID;
    float sum = 0.0f, mx = -3.402823e38f;
    for (int n = half * 256; n < half * 256 + 256; n++) {
        const float v = hb[(size_t)n * HID + c];
        sum += v; mx = fmaxf(mx, v);
    }
    __shared__ float ssum[128], smx[128];
    if (half) { ssum[c] = sum; smx[c] = mx; }
    __syncthreads();
    if (!half) {
        sum += ssum[c];
        mx = fmaxf(mx, smx[c]);
        float* grow = g + (size_t)gr * H6 + conv * 256;
        grow[c]       = sum * (1.0f / 512.0f);
        grow[128 + c] = mx;
    }
}

// ---------------------------------------------------------------------------
// Head layer: gout(16,768) = leaky(gin @ W + b). Grid = 16 rows x 6 colchunks
// = 96 blocks x 256 threads. Thread = (col-in-chunk, k-half); k split in two
// 384-ranges with 4 sub-accumulators each; LDS reduce. BN fused into the
// g-row staging of layer 0.
// ---------------------------------------------------------------------------
template<bool BN>
__global__ __launch_bounds__(256) void lin_kernel(const float* __restrict__ gin,
                                                  const float* __restrict__ W,
                                                  const float* __restrict__ bias,
                                                  float* __restrict__ gout,
                                                  const float* __restrict__ gamma,
                                                  const float* __restrict__ beta,
                                                  const float* __restrict__ mean,
                                                  const float* __restrict__ var) {
    const int r   = blockIdx.x / 6;
    const int cc  = blockIdx.x % 6;
    const int tid = threadIdx.x;

    __shared__ float gs[H6];
    for (int k = tid; k < H6; k += 256) {
        float v = gin[(size_t)r * H6 + k];
        if (BN) v = (v - mean[k]) * (1.0f / sqrtf(var[k] + 1e-5f)) * gamma[k] + beta[k];
        gs[k] = v;
    }
    __syncthreads();

    const int c  = cc * 128 + (tid & 127);
    const int kh = tid >> 7;
    const int kb = kh * 384;
    float a0=0.f,a1=0.f,a2=0.f,a3=0.f;
    for (int k = kb; k < kb + 384; k += 4) {
        a0 += gs[k]     * W[(size_t)(k)     * H6 + c];
        a1 += gs[k + 1] * W[(size_t)(k + 1) * H6 + c];
        a2 += gs[k + 2] * W[(size_t)(k + 2) * H6 + c];
        a3 += gs[k + 3] * W[(size_t)(k + 3) * H6 + c];
    }
    __shared__ float part[256];
    part[tid] = (a0 + a1) + (a2 + a3);
    __syncthreads();
    if (kh == 0) {
        const float v = part[tid] + part[tid + 128] + bias[c];
        gout[(size_t)r * H6 + c] = leaky(v);
    }
}

// out(16,3) = g @ out_w + out_b. 192 threads: (r,c) x 4 k-chunks, LDS reduce.
__global__ void out_kernel(const float* __restrict__ gin,
                           const float* __restrict__ W,
                           const float* __restrict__ bias,
                           float* __restrict__ out) {
    const int tid = threadIdx.x;
    __shared__ float part[192];
    if (tid < 192) {
        const int q  = tid >> 2;        // 0..47
        const int r  = q / 3, c = q % 3;
        const int kq = tid & 3;
        float acc = 0.0f;
        for (int k = kq * 192; k < kq * 192 + 192; k++)
            acc += gin[(size_t)r * H6 + k] * W[(size_t)k * 3 + c];
        part[tid] = acc;
    }
    __syncthreads();
    if (tid < 48) {
        const int r = tid / 3, c = tid % 3;
        out[r * 3 + c] = part[tid*4] + part[tid*4+1] + part[tid*4+2] + part[tid*4+3] + bias[c];
    }
}

// ---------------------------------------------------------------------------
extern "C" void kernel_launch(void* const* d_in, const int* in_sizes, int n_in,
                              void* d_out, int out_size, void* d_ws, size_t ws_size,
                              hipStream_t stream) {
    const float* x        = (const float*)d_in[0];
    // d_in[1] = batch: contiguous 512-node blocks by construction; unused.
    const float* conv1_w  = (const float*)d_in[2];
    const float* conv1_b  = (const float*)d_in[3];
    const float* conv2_w  = (const float*)d_in[4];
    const float* conv2_b  = (const float*)d_in[5];
    const float* conv3_w  = (const float*)d_in[6];
    const float* conv3_b  = (const float*)d_in[7];
    const float* bn_gamma = (const float*)d_in[8];
    const float* bn_beta  = (const float*)d_in[9];
    const float* bn_mean  = (const float*)d_in[10];
    const float* bn_var   = (const float*)d_in[11];
    const float* lin_w    = (const float*)d_in[12];
    const float* lin_b    = (const float*)d_in[13];
    const float* out_w    = (const float*)d_in[14];
    const float* out_b    = (const float*)d_in[15];

    char* ws = (char*)d_ws;
    size_t off = 0;
    auto alloc = [&](size_t bytes) {
        void* p = ws + off;
        off += (bytes + 255) & ~(size_t)255;
        return p;
    };
    int*   nbr = (int*)  alloc((size_t)N * KNN * 4);
    float* y6a = (float*)alloc((size_t)N * F0 * 4);
    float* y6b = (float*)alloc((size_t)N * F0 * 4);
    float* hA  = (float*)alloc((size_t)N * HID * 4);
    float* hB  = (float*)alloc((size_t)N * HID * 4);
    float* y1  = (float*)alloc((size_t)N * HID * 4);
    float* y2  = (float*)alloc((size_t)N * HID * 4);
    float* ga  = (float*)alloc((size_t)NG * H6 * 4);
    float* gb  = (float*)alloc((size_t)NG * H6 * 4);

    knn_kernel<<<N, 256, 0, stream>>>(x, nbr);

    // conv1 (K=6)
    prop6<<<N / 256, 256, 0, stream>>>(x, nbr, y6a);
    prop6<<<N / 256, 256, 0, stream>>>(y6a, nbr, y6b);
    combine_kernel<6><<<N / 16, 256, 0, stream>>>(x, y6a, y6b, conv1_w, conv1_b, hA);
    pool_kernel<<<NG, 256, 0, stream>>>(hA, ga, 0);

    // conv2 (K=128)
    prop128<<<N / 8, 256, 0, stream>>>(hA, nbr, y1);
    prop128<<<N / 8, 256, 0, stream>>>(y1, nbr, y2);
    combine_kernel<128><<<N / 16, 256, 0, stream>>>(hA, y1, y2, conv2_w, conv2_b, hB);
    pool_kernel<<<NG, 256, 0, stream>>>(hB, ga, 1);

    // conv3 (K=128)
    prop128<<<N / 8, 256, 0, stream>>>(hB, nbr, y1);
    prop128<<<N / 8, 256, 0, stream>>>(y1, nbr, y2);
    combine_kernel<128><<<N / 16, 256, 0, stream>>>(hB, y1, y2, conv3_w, conv3_b, hA);
    pool_kernel<<<NG, 256, 0, stream>>>(hA, ga, 2);

    // head (BN fused into first layer's staging)
    lin_kernel<true ><<<96, 256, 0, stream>>>(ga, lin_w + 0 * H6 * H6, lin_b + 0 * H6, gb,
                                              bn_gamma, bn_beta, bn_mean, bn_var);
    lin_kernel<false><<<96, 256, 0, stream>>>(gb, lin_w + 1 * H6 * H6, lin_b + 1 * H6, ga,
                                              nullptr, nullptr, nullptr, nullptr);
    lin_kernel<false><<<96, 256, 0, stream>>>(ga, lin_w + 2 * H6 * H6, lin_b + 2 * H6, gb,
                                              nullptr, nullptr, nullptr, nullptr);
    lin_kernel<false><<<96, 256, 0, stream>>>(gb, lin_w + 3 * H6 * H6, lin_b + 3 * H6, ga,
                                              nullptr, nullptr, nullptr, nullptr);
    lin_kernel<false><<<96, 256, 0, stream>>>(ga, lin_w + 4 * H6 * H6, lin_b + 4 * H6, gb,
                                              nullptr, nullptr, nullptr, nullptr);
    out_kernel<<<1, 256, 0, stream>>>(gb, out_w, out_b, (float*)d_out);
}

// Round 3
// 502.596 us; speedup vs baseline: 1.9253x; 1.1351x over previous
//
#include <hip/hip_runtime.h>

constexpr int N    = 8192;
constexpr int NPG  = 512;   // nodes per graph
constexpr int NG   = 16;
constexpr int KNN  = 80;
constexpr int F0   = 6;
constexpr int HID  = 128;
constexpr int H6   = 768;

__device__ __forceinline__ float leaky(float v) { return v > 0.0f ? v : 0.01f * v; }

__device__ __forceinline__ int lanes_below(unsigned long long m) {
    return __builtin_amdgcn_mbcnt_hi((unsigned)(m >> 32),
           __builtin_amdgcn_mbcnt_lo((unsigned)m, 0));
}

// wave-sum of a per-lane count in [0,8] via 4 ballots (result uniform)
__device__ __forceinline__ int wave_count_sum(int c) {
    int total = 0;
    #pragma unroll
    for (int b = 0; b < 4; b++)
        total += (int)__popcll(__ballot((c >> b) & 1)) << b;
    return total;
}

// ---------------------------------------------------------------------------
// KNN, wave-per-target. Block = 256 threads = 4 waves = 4 targets, all in the
// same 512-node graph. Positions staged SoA in LDS (2-way bank alias = free).
// Each lane holds 8 candidates' mapped-d2 in registers. Exact rank-79
// threshold via 32-step binary search on the monotonic u32 map (wave-uniform
// ballot counts); ties at V taken in ascending node order == jax.lax.top_k
// stable tie semantics. The exactly-80 survivors are compacted to LDS and
// bitonic-sorted (128 elems, 28 stages, 1 cmp/lane) for (d2,idx) order.
// ---------------------------------------------------------------------------
__global__ __launch_bounds__(256) void knn_kernel(const float* __restrict__ x,
                                                  int* __restrict__ nbr) {
    constexpr int BPG = 128;               // blocks per graph (4 targets each)
    const int tid  = threadIdx.x;
    const int lane = tid & 63;
    const int wv   = tid >> 6;
    const int base = (blockIdx.x / BPG) << 9;
    const int t    = base + (blockIdx.x & (BPG - 1)) * 4 + wv;
    const int tl   = t - base;

    __shared__ float px[512], py[512], pz[512], pw[512];
    __shared__ unsigned long long skey[4 * 128];

    for (int j = tid; j < 512; j += 256) {
        const float* row = x + (size_t)(base + j) * F0;
        const float2 ra = *(const float2*)(row);
        const float2 rb = *(const float2*)(row + 2);
        px[j] = ra.x; py[j] = ra.y; pz[j] = rb.x; pw[j] = rb.y;
    }
    __syncthreads();

    const float tx = px[tl], ty = py[tl], tz = pz[tl], tw = pw[tl];
    const float sqt = tx*tx + ty*ty + tz*tz + tw*tw;

    unsigned d2m[8];
    #pragma unroll
    for (int j = 0; j < 8; j++) {
        const int node = j * 64 + lane;
        const float jx = px[node], jy = py[node], jz = pz[node], jw = pw[node];
        const float sqj = jx*jx + jy*jy + jz*jz + jw*jw;
        const float dot = tx*jx + ty*jy + tz*jz + tw*jw;
        const float d2  = sqt + sqj - 2.0f * dot;
        unsigned u = __float_as_uint(d2);
        u = (u & 0x80000000u) ? ~u : (u | 0x80000000u);   // monotonic map
        d2m[j] = (node == tl) ? 0xFFFFFFFFu : u;          // exclude self
    }

    // ---- binary search for V = rank-79 (0-indexed) smallest mapped d2 ----
    unsigned V = 0;
    for (int b = 31; b >= 0; --b) {
        const unsigned test = V | (1u << b);
        int c = 0;
        #pragma unroll
        for (int j = 0; j < 8; j++) c += (d2m[j] < test) ? 1 : 0;
        if (wave_count_sum(c) < KNN) V = test;
    }

    // n_lt = #keys strictly below V
    int c = 0;
    #pragma unroll
    for (int j = 0; j < 8; j++) c += (d2m[j] < V) ? 1 : 0;
    const int n_lt = wave_count_sum(c);
    const int need = KNN - n_lt;           // ties at V to take, by node order

    // ---- select + compact exactly 80 keys into this wave's LDS region ----
    const int woff = wv * 128;
    int cnt_total = 0, taken = 0;
    #pragma unroll
    for (int j = 0; j < 8; j++) {
        const bool lt = d2m[j] < V;
        const bool eq = d2m[j] == V;
        const unsigned long long meq = __ballot(eq);
        const bool sel = lt || (eq && (taken + lanes_below(meq)) < need);
        taken += (int)__popcll(meq);
        const unsigned long long msel = __ballot(sel);
        if (sel) {
            const int pos = cnt_total + lanes_below(msel);
            skey[woff + pos] = ((unsigned long long)d2m[j] << 32)
                             | (unsigned)(base + j * 64 + lane);
        }
        cnt_total += (int)__popcll(msel);
    }
    for (int i = KNN + lane; i < 128; i += 64) skey[woff + i] = ~0ULL;
    __syncthreads();

    // ---- bitonic sort 128 (each wave sorts its own region; uniform loops) --
    for (int kk = 2; kk <= 128; kk <<= 1) {
        for (int jj = kk >> 1; jj >= 1; jj >>= 1) {
            const int i  = ((lane & ~(jj - 1)) << 1) | (lane & (jj - 1));
            const int ix = i | jj;
            const unsigned long long a = skey[woff + i];
            const unsigned long long b = skey[woff + ix];
            const bool up = ((i & kk) == 0);
            if ((a > b) == up) { skey[woff + i] = b; skey[woff + ix] = a; }
            __syncthreads();
        }
    }

    if (lane < KNN)      nbr[t * KNN + lane]      = (int)(unsigned)skey[woff + lane];
    if (lane + 64 < KNN) nbr[t * KNN + lane + 64] = (int)(unsigned)skey[woff + lane + 64];
}

// ---------------------------------------------------------------------------
// Propagation Y[t] = (1/80) * sum_{s in nbr(t)} H[s]
// ---------------------------------------------------------------------------
__global__ __launch_bounds__(256) void prop6(const float* __restrict__ hin,
                                             const int* __restrict__ nbr,
                                             float* __restrict__ hout) {
    const int t = blockIdx.x * 256 + threadIdx.x;
    if (t >= N) return;
    const int* nb = nbr + t * KNN;
    float a0=0.f,a1=0.f,a2=0.f,a3=0.f,a4=0.f,a5=0.f;
    for (int i = 0; i < KNN; i += 4) {
        const int4 s4 = *(const int4*)(nb + i);
        {   const float* r = hin + (size_t)s4.x * F0;
            a0+=r[0]; a1+=r[1]; a2+=r[2]; a3+=r[3]; a4+=r[4]; a5+=r[5]; }
        {   const float* r = hin + (size_t)s4.y * F0;
            a0+=r[0]; a1+=r[1]; a2+=r[2]; a3+=r[3]; a4+=r[4]; a5+=r[5]; }
        {   const float* r = hin + (size_t)s4.z * F0;
            a0+=r[0]; a1+=r[1]; a2+=r[2]; a3+=r[3]; a4+=r[4]; a5+=r[5]; }
        {   const float* r = hin + (size_t)s4.w * F0;
            a0+=r[0]; a1+=r[1]; a2+=r[2]; a3+=r[3]; a4+=r[4]; a5+=r[5]; }
    }
    const float inv = 1.0f / 80.0f;
    float* o = hout + (size_t)t * F0;
    o[0]=a0*inv; o[1]=a1*inv; o[2]=a2*inv; o[3]=a3*inv; o[4]=a4*inv; o[5]=a5*inv;
}

// 32 lanes per target (float4 each), 16 gathers in flight, 128-thread blocks.
__global__ __launch_bounds__(128) void prop128(const float* __restrict__ hin,
                                               const int* __restrict__ nbr,
                                               float* __restrict__ hout) {
    const int lane = threadIdx.x & 31;
    const int t    = blockIdx.x * 4 + (threadIdx.x >> 5);
    const int* nb  = nbr + t * KNN;
    float a0=0.f,a1=0.f,a2=0.f,a3=0.f;
    for (int i = 0; i < KNN; i += 16) {
        const int4 sA = *(const int4*)(nb + i);
        const int4 sB = *(const int4*)(nb + i + 4);
        const int4 sC = *(const int4*)(nb + i + 8);
        const int4 sD = *(const int4*)(nb + i + 12);
        const int idx[16] = {sA.x,sA.y,sA.z,sA.w, sB.x,sB.y,sB.z,sB.w,
                             sC.x,sC.y,sC.z,sC.w, sD.x,sD.y,sD.z,sD.w};
        float4 v[16];
        #pragma unroll
        for (int q = 0; q < 16; q++)
            v[q] = *(const float4*)(hin + (size_t)idx[q] * HID + lane * 4);
        #pragma unroll
        for (int q = 0; q < 16; q += 4) {
            a0 += (v[q].x + v[q+1].x) + (v[q+2].x + v[q+3].x);
            a1 += (v[q].y + v[q+1].y) + (v[q+2].y + v[q+3].y);
            a2 += (v[q].z + v[q+1].z) + (v[q+2].z + v[q+3].z);
            a3 += (v[q].w + v[q+1].w) + (v[q+2].w + v[q+3].w);
        }
    }
    const float inv = 1.0f / 80.0f;
    float4 r; r.x=a0*inv; r.y=a1*inv; r.z=a2*inv; r.w=a3*inv;
    *(float4*)(hout + (size_t)t * HID + lane * 4) = r;
}

// ---------------------------------------------------------------------------
// Fused TAGConv combine as LDS-tiled GEMM (16 rows x 128 cols per block).
// ---------------------------------------------------------------------------
template<int K>
__global__ __launch_bounds__(256) void combine_kernel(const float* __restrict__ X,
                                                      const float* __restrict__ Y1,
                                                      const float* __restrict__ Y2,
                                                      const float* __restrict__ W,
                                                      const float* __restrict__ bias,
                                                      float* __restrict__ out) {
    __shared__ float xs[3][16 * K];
    const int tid  = threadIdx.x;
    const int row0 = blockIdx.x * 16;

    {
        const float* s0 = X  + (size_t)row0 * K;
        const float* s1 = Y1 + (size_t)row0 * K;
        const float* s2 = Y2 + (size_t)row0 * K;
        if constexpr ((K & 3) == 0) {
            constexpr int NV = 16 * K / 4;
            for (int i = tid; i < NV; i += 256) ((float4*)xs[0])[i] = ((const float4*)s0)[i];
            for (int i = tid; i < NV; i += 256) ((float4*)xs[1])[i] = ((const float4*)s1)[i];
            for (int i = tid; i < NV; i += 256) ((float4*)xs[2])[i] = ((const float4*)s2)[i];
        } else {
            for (int i = tid; i < 16 * K; i += 256) xs[0][i] = s0[i];
            for (int i = tid; i < 16 * K; i += 256) xs[1][i] = s1[i];
            for (int i = tid; i < 16 * K; i += 256) xs[2][i] = s2[i];
        }
    }
    __syncthreads();

    const int c  = tid & 127;
    const int r0 = (tid >> 7) * 8;      // 0 or 8

    float acc[8];
    #pragma unroll
    for (int r = 0; r < 8; r++) acc[r] = 0.0f;

    #pragma unroll
    for (int s = 0; s < 3; s++) {
        const float* __restrict__ Ws   = W + (size_t)s * K * HID;
        const float* __restrict__ xseg = xs[s] + r0 * K;
        for (int k = 0; k < K; k += 2) {
            const float w0 = Ws[(size_t)k * HID + c];
            const float w1 = Ws[(size_t)(k + 1) * HID + c];
            #pragma unroll
            for (int r = 0; r < 8; r++)
                acc[r] += xseg[r * K + k] * w0 + xseg[r * K + k + 1] * w1;
        }
    }

    const float bb = bias[c];
    #pragma unroll
    for (int r = 0; r < 8; r++)
        out[(size_t)(row0 + r0 + r) * HID + c] = leaky(acc[r] + bb);
}

// ---------------------------------------------------------------------------
__global__ __launch_bounds__(256) void pool_kernel(const float* __restrict__ h,
                                                   float* __restrict__ g, int conv) {
    const int gr   = blockIdx.x;
    const int c    = threadIdx.x & 127;
    const int half = threadIdx.x >> 7;
    const float* hb = h + (size_t)gr * NPG * HID;
    float sum = 0.0f, mx = -3.402823e38f;
    for (int n = half * 256; n < half * 256 + 256; n++) {
        const float v = hb[(size_t)n * HID + c];
        sum += v; mx = fmaxf(mx, v);
    }
    __shared__ float ssum[128], smx[128];
    if (half) { ssum[c] = sum; smx[c] = mx; }
    __syncthreads();
    if (!half) {
        sum += ssum[c];
        mx = fmaxf(mx, smx[c]);
        float* grow = g + (size_t)gr * H6 + conv * 256;
        grow[c]       = sum * (1.0f / 512.0f);
        grow[128 + c] = mx;
    }
}

// ---------------------------------------------------------------------------
template<bool BN>
__global__ __launch_bounds__(256) void lin_kernel(const float* __restrict__ gin,
                                                  const float* __restrict__ W,
                                                  const float* __restrict__ bias,
                                                  float* __restrict__ gout,
                                                  const float* __restrict__ gamma,
                                                  const float* __restrict__ beta,
                                                  const float* __restrict__ mean,
                                                  const float* __restrict__ var) {
    const int r   = blockIdx.x / 6;
    const int cc  = blockIdx.x % 6;
    const int tid = threadIdx.x;

    __shared__ float gs[H6];
    for (int k = tid; k < H6; k += 256) {
        float v = gin[(size_t)r * H6 + k];
        if (BN) v = (v - mean[k]) * (1.0f / sqrtf(var[k] + 1e-5f)) * gamma[k] + beta[k];
        gs[k] = v;
    }
    __syncthreads();

    const int c  = cc * 128 + (tid & 127);
    const int kh = tid >> 7;
    const int kb = kh * 384;
    float a0=0.f,a1=0.f,a2=0.f,a3=0.f;
    for (int k = kb; k < kb + 384; k += 4) {
        a0 += gs[k]     * W[(size_t)(k)     * H6 + c];
        a1 += gs[k + 1] * W[(size_t)(k + 1) * H6 + c];
        a2 += gs[k + 2] * W[(size_t)(k + 2) * H6 + c];
        a3 += gs[k + 3] * W[(size_t)(k + 3) * H6 + c];
    }
    __shared__ float part[256];
    part[tid] = (a0 + a1) + (a2 + a3);
    __syncthreads();
    if (kh == 0) {
        const float v = part[tid] + part[tid + 128] + bias[c];
        gout[(size_t)r * H6 + c] = leaky(v);
    }
}

__global__ void out_kernel(const float* __restrict__ gin,
                           const float* __restrict__ W,
                           const float* __restrict__ bias,
                           float* __restrict__ out) {
    const int tid = threadIdx.x;
    __shared__ float part[192];
    if (tid < 192) {
        const int q  = tid >> 2;        // 0..47
        const int r  = q / 3, c = q % 3;
        const int kq = tid & 3;
        float acc = 0.0f;
        for (int k = kq * 192; k < kq * 192 + 192; k++)
            acc += gin[(size_t)r * H6 + k] * W[(size_t)k * 3 + c];
        part[tid] = acc;
    }
    __syncthreads();
    if (tid < 48) {
        const int r = tid / 3, c = tid % 3;
        out[r * 3 + c] = part[tid*4] + part[tid*4+1] + part[tid*4+2] + part[tid*4+3] + bias[c];
    }
}

// ---------------------------------------------------------------------------
extern "C" void kernel_launch(void* const* d_in, const int* in_sizes, int n_in,
                              void* d_out, int out_size, void* d_ws, size_t ws_size,
                              hipStream_t stream) {
    const float* x        = (const float*)d_in[0];
    const float* conv1_w  = (const float*)d_in[2];
    const float* conv1_b  = (const float*)d_in[3];
    const float* conv2_w  = (const float*)d_in[4];
    const float* conv2_b  = (const float*)d_in[5];
    const float* conv3_w  = (const float*)d_in[6];
    const float* conv3_b  = (const float*)d_in[7];
    const float* bn_gamma = (const float*)d_in[8];
    const float* bn_beta  = (const float*)d_in[9];
    const float* bn_mean  = (const float*)d_in[10];
    const float* bn_var   = (const float*)d_in[11];
    const float* lin_w    = (const float*)d_in[12];
    const float* lin_b    = (const float*)d_in[13];
    const float* out_w    = (const float*)d_in[14];
    const float* out_b    = (const float*)d_in[15];

    char* ws = (char*)d_ws;
    size_t off = 0;
    auto alloc = [&](size_t bytes) {
        void* p = ws + off;
        off += (bytes + 255) & ~(size_t)255;
        return p;
    };
    int*   nbr = (int*)  alloc((size_t)N * KNN * 4);
    float* y6a = (float*)alloc((size_t)N * F0 * 4);
    float* y6b = (float*)alloc((size_t)N * F0 * 4);
    float* hA  = (float*)alloc((size_t)N * HID * 4);
    float* hB  = (float*)alloc((size_t)N * HID * 4);
    float* y1  = (float*)alloc((size_t)N * HID * 4);
    float* y2  = (float*)alloc((size_t)N * HID * 4);
    float* ga  = (float*)alloc((size_t)NG * H6 * 4);
    float* gb  = (float*)alloc((size_t)NG * H6 * 4);

    knn_kernel<<<N / 4, 256, 0, stream>>>(x, nbr);

    // conv1 (K=6)
    prop6<<<N / 256, 256, 0, stream>>>(x, nbr, y6a);
    prop6<<<N / 256, 256, 0, stream>>>(y6a, nbr, y6b);
    combine_kernel<6><<<N / 16, 256, 0, stream>>>(x, y6a, y6b, conv1_w, conv1_b, hA);
    pool_kernel<<<NG, 256, 0, stream>>>(hA, ga, 0);

    // conv2 (K=128)
    prop128<<<N / 4, 128, 0, stream>>>(hA, nbr, y1);
    prop128<<<N / 4, 128, 0, stream>>>(y1, nbr, y2);
    combine_kernel<128><<<N / 16, 256, 0, stream>>>(hA, y1, y2, conv2_w, conv2_b, hB);
    pool_kernel<<<NG, 256, 0, stream>>>(hB, ga, 1);

    // conv3 (K=128)
    prop128<<<N / 4, 128, 0, stream>>>(hB, nbr, y1);
    prop128<<<N / 4, 128, 0, stream>>>(y1, nbr, y2);
    combine_kernel<128><<<N / 16, 256, 0, stream>>>(hB, y1, y2, conv3_w, conv3_b, hA);
    pool_kernel<<<NG, 256, 0, stream>>>(hA, ga, 2);

    // head (BN fused into first layer's staging)
    lin_kernel<true ><<<96, 256, 0, stream>>>(ga, lin_w + 0 * H6 * H6, lin_b + 0 * H6, gb,
                                              bn_gamma, bn_beta, bn_mean, bn_var);
    lin_kernel<false><<<96, 256, 0, stream>>>(gb, lin_w + 1 * H6 * H6, lin_b + 1 * H6, ga,
                                              nullptr, nullptr, nullptr, nullptr);
    lin_kernel<false><<<96, 256, 0, stream>>>(ga, lin_w + 2 * H6 * H6, lin_b + 2 * H6, gb,
                                              nullptr, nullptr, nullptr, nullptr);
    lin_kernel<false><<<96, 256, 0, stream>>>(gb, lin_w + 3 * H6 * H6, lin_b + 3 * H6, ga,
                                              nullptr, nullptr, nullptr, nullptr);
    lin_kernel<false><<<96, 256, 0, stream>>>(ga, lin_w + 4 * H6 * H6, lin_b + 4 * H6, gb,
                                              nullptr, nullptr, nullptr, nullptr);
    out_kernel<<<1, 256, 0, stream>>>(gb, out_w, out_b, (float*)d_out);
}

// Round 4
// 292.120 us; speedup vs baseline: 3.3125x; 1.7205x over previous
//
#include <hip/hip_runtime.h>

constexpr int N    = 8192;
constexpr int NPG  = 512;   // nodes per graph
constexpr int NG   = 16;
constexpr int KNN  = 80;
constexpr int F0   = 6;
constexpr int HID  = 128;
constexpr int H6   = 768;
constexpr int RPB  = 16;    // rows per combine block
constexpr int BPGR = NPG / RPB;  // combine blocks per graph = 32

__device__ __forceinline__ float leaky(float v) { return v > 0.0f ? v : 0.01f * v; }

__device__ __forceinline__ int lanes_below(unsigned long long m) {
    return __builtin_amdgcn_mbcnt_hi((unsigned)(m >> 32),
           __builtin_amdgcn_mbcnt_lo((unsigned)m, 0));
}

// wave-sum of a per-lane count in [0,8] via 4 ballots (result uniform)
__device__ __forceinline__ int wave_count_sum(int c) {
    int total = 0;
    #pragma unroll
    for (int b = 0; b < 4; b++)
        total += (int)__popcll(__ballot((c >> b) & 1)) << b;
    return total;
}

// ---------------------------------------------------------------------------
// KNN, wave-per-target (see R2 notes): exact rank-79 threshold via 32-step
// binary search on monotonic-mapped d2, tie-break by node order, 128-elem
// bitonic sort for output order.
// ---------------------------------------------------------------------------
__global__ __launch_bounds__(256) void knn_kernel(const float* __restrict__ x,
                                                  int* __restrict__ nbr) {
    constexpr int BPG = 128;               // blocks per graph (4 targets each)
    const int tid  = threadIdx.x;
    const int lane = tid & 63;
    const int wv   = tid >> 6;
    const int base = (blockIdx.x / BPG) << 9;
    const int t    = base + (blockIdx.x & (BPG - 1)) * 4 + wv;
    const int tl   = t - base;

    __shared__ float px[512], py[512], pz[512], pw[512];
    __shared__ unsigned long long skey[4 * 128];

    for (int j = tid; j < 512; j += 256) {
        const float* row = x + (size_t)(base + j) * F0;
        const float2 ra = *(const float2*)(row);
        const float2 rb = *(const float2*)(row + 2);
        px[j] = ra.x; py[j] = ra.y; pz[j] = rb.x; pw[j] = rb.y;
    }
    __syncthreads();

    const float tx = px[tl], ty = py[tl], tz = pz[tl], tw = pw[tl];
    const float sqt = tx*tx + ty*ty + tz*tz + tw*tw;

    unsigned d2m[8];
    #pragma unroll
    for (int j = 0; j < 8; j++) {
        const int node = j * 64 + lane;
        const float jx = px[node], jy = py[node], jz = pz[node], jw = pw[node];
        const float sqj = jx*jx + jy*jy + jz*jz + jw*jw;
        const float dot = tx*jx + ty*jy + tz*jz + tw*jw;
        const float d2  = sqt + sqj - 2.0f * dot;
        unsigned u = __float_as_uint(d2);
        u = (u & 0x80000000u) ? ~u : (u | 0x80000000u);   // monotonic map
        d2m[j] = (node == tl) ? 0xFFFFFFFFu : u;          // exclude self
    }

    unsigned V = 0;
    for (int b = 31; b >= 0; --b) {
        const unsigned test = V | (1u << b);
        int c = 0;
        #pragma unroll
        for (int j = 0; j < 8; j++) c += (d2m[j] < test) ? 1 : 0;
        if (wave_count_sum(c) < KNN) V = test;
    }

    int c = 0;
    #pragma unroll
    for (int j = 0; j < 8; j++) c += (d2m[j] < V) ? 1 : 0;
    const int n_lt = wave_count_sum(c);
    const int need = KNN - n_lt;

    const int woff = wv * 128;
    int cnt_total = 0, taken = 0;
    #pragma unroll
    for (int j = 0; j < 8; j++) {
        const bool lt = d2m[j] < V;
        const bool eq = d2m[j] == V;
        const unsigned long long meq = __ballot(eq);
        const bool sel = lt || (eq && (taken + lanes_below(meq)) < need);
        taken += (int)__popcll(meq);
        const unsigned long long msel = __ballot(sel);
        if (sel) {
            const int pos = cnt_total + lanes_below(msel);
            skey[woff + pos] = ((unsigned long long)d2m[j] << 32)
                             | (unsigned)(base + j * 64 + lane);
        }
        cnt_total += (int)__popcll(msel);
    }
    for (int i = KNN + lane; i < 128; i += 64) skey[woff + i] = ~0ULL;
    __syncthreads();

    for (int kk = 2; kk <= 128; kk <<= 1) {
        for (int jj = kk >> 1; jj >= 1; jj >>= 1) {
            const int i  = ((lane & ~(jj - 1)) << 1) | (lane & (jj - 1));
            const int ix = i | jj;
            const unsigned long long a = skey[woff + i];
            const unsigned long long b = skey[woff + ix];
            const bool up = ((i & kk) == 0);
            if ((a > b) == up) { skey[woff + i] = b; skey[woff + ix] = a; }
            __syncthreads();
        }
    }

    if (lane < KNN)      nbr[t * KNN + lane]      = (int)(unsigned)skey[woff + lane];
    if (lane + 64 < KNN) nbr[t * KNN + lane + 64] = (int)(unsigned)skey[woff + lane + 64];
}

// ---------------------------------------------------------------------------
// Propagation Y[t] = (1/80) * sum_{s in nbr(t)} H[s]
// ---------------------------------------------------------------------------
__global__ __launch_bounds__(256) void prop6(const float* __restrict__ hin,
                                             const int* __restrict__ nbr,
                                             float* __restrict__ hout) {
    const int t = blockIdx.x * 256 + threadIdx.x;
    if (t >= N) return;
    const int* nb = nbr + t * KNN;
    float a0=0.f,a1=0.f,a2=0.f,a3=0.f,a4=0.f,a5=0.f;
    for (int i = 0; i < KNN; i += 4) {
        const int4 s4 = *(const int4*)(nb + i);
        {   const float* r = hin + (size_t)s4.x * F0;
            a0+=r[0]; a1+=r[1]; a2+=r[2]; a3+=r[3]; a4+=r[4]; a5+=r[5]; }
        {   const float* r = hin + (size_t)s4.y * F0;
            a0+=r[0]; a1+=r[1]; a2+=r[2]; a3+=r[3]; a4+=r[4]; a5+=r[5]; }
        {   const float* r = hin + (size_t)s4.z * F0;
            a0+=r[0]; a1+=r[1]; a2+=r[2]; a3+=r[3]; a4+=r[4]; a5+=r[5]; }
        {   const float* r = hin + (size_t)s4.w * F0;
            a0+=r[0]; a1+=r[1]; a2+=r[2]; a3+=r[3]; a4+=r[4]; a5+=r[5]; }
    }
    const float inv = 1.0f / 80.0f;
    float* o = hout + (size_t)t * F0;
    o[0]=a0*inv; o[1]=a1*inv; o[2]=a2*inv; o[3]=a3*inv; o[4]=a4*inv; o[5]=a5*inv;
}

// 32 lanes per target (float4 each), 16 gathers in flight, 128-thread blocks.
__global__ __launch_bounds__(128) void prop128(const float* __restrict__ hin,
                                               const int* __restrict__ nbr,
                                               float* __restrict__ hout) {
    const int lane = threadIdx.x & 31;
    const int t    = blockIdx.x * 4 + (threadIdx.x >> 5);
    const int* nb  = nbr + t * KNN;
    float a0=0.f,a1=0.f,a2=0.f,a3=0.f;
    for (int i = 0; i < KNN; i += 16) {
        const int4 sA = *(const int4*)(nb + i);
        const int4 sB = *(const int4*)(nb + i + 4);
        const int4 sC = *(const int4*)(nb + i + 8);
        const int4 sD = *(const int4*)(nb + i + 12);
        const int idx[16] = {sA.x,sA.y,sA.z,sA.w, sB.x,sB.y,sB.z,sB.w,
                             sC.x,sC.y,sC.z,sC.w, sD.x,sD.y,sD.z,sD.w};
        float4 v[16];
        #pragma unroll
        for (int q = 0; q < 16; q++)
            v[q] = *(const float4*)(hin + (size_t)idx[q] * HID + lane * 4);
        #pragma unroll
        for (int q = 0; q < 16; q += 4) {
            a0 += (v[q].x + v[q+1].x) + (v[q+2].x + v[q+3].x);
            a1 += (v[q].y + v[q+1].y) + (v[q+2].y + v[q+3].y);
            a2 += (v[q].z + v[q+1].z) + (v[q+2].z + v[q+3].z);
            a3 += (v[q].w + v[q+1].w) + (v[q+2].w + v[q+3].w);
        }
    }
    const float inv = 1.0f / 80.0f;
    float4 r; r.x=a0*inv; r.y=a1*inv; r.z=a2*inv; r.w=a3*inv;
    *(float4*)(hout + (size_t)t * HID + lane * 4) = r;
}

// ---------------------------------------------------------------------------
// Fused TAGConv combine as LDS-tiled GEMM (16 rows x 128 cols per block)
// + fused partial mean/max pool: each block emits psum/pmax per column.
// ---------------------------------------------------------------------------
template<int K>
__global__ __launch_bounds__(256) void combine_kernel(const float* __restrict__ X,
                                                      const float* __restrict__ Y1,
                                                      const float* __restrict__ Y2,
                                                      const float* __restrict__ W,
                                                      const float* __restrict__ bias,
                                                      float* __restrict__ out,
                                                      float* __restrict__ psum,
                                                      float* __restrict__ pmax) {
    __shared__ float xs[3][RPB * K];
    const int tid  = threadIdx.x;
    const int row0 = blockIdx.x * RPB;

    {
        const float* s0 = X  + (size_t)row0 * K;
        const float* s1 = Y1 + (size_t)row0 * K;
        const float* s2 = Y2 + (size_t)row0 * K;
        if constexpr ((K & 3) == 0) {
            constexpr int NV = RPB * K / 4;
            for (int i = tid; i < NV; i += 256) ((float4*)xs[0])[i] = ((const float4*)s0)[i];
            for (int i = tid; i < NV; i += 256) ((float4*)xs[1])[i] = ((const float4*)s1)[i];
            for (int i = tid; i < NV; i += 256) ((float4*)xs[2])[i] = ((const float4*)s2)[i];
        } else {
            for (int i = tid; i < RPB * K; i += 256) xs[0][i] = s0[i];
            for (int i = tid; i < RPB * K; i += 256) xs[1][i] = s1[i];
            for (int i = tid; i < RPB * K; i += 256) xs[2][i] = s2[i];
        }
    }
    __syncthreads();

    const int c  = tid & 127;
    const int r0 = (tid >> 7) * 8;      // 0 or 8

    float acc[8];
    #pragma unroll
    for (int r = 0; r < 8; r++) acc[r] = 0.0f;

    #pragma unroll
    for (int s = 0; s < 3; s++) {
        const float* __restrict__ Ws   = W + (size_t)s * K * HID;
        const float* __restrict__ xseg = xs[s] + r0 * K;
        for (int k = 0; k < K; k += 2) {
            const float w0 = Ws[(size_t)k * HID + c];
            const float w1 = Ws[(size_t)(k + 1) * HID + c];
            #pragma unroll
            for (int r = 0; r < 8; r++)
                acc[r] += xseg[r * K + k] * w0 + xseg[r * K + k + 1] * w1;
        }
    }

    const float bb = bias[c];
    float sum8 = 0.0f, mx8 = -3.402823e38f;
    #pragma unroll
    for (int r = 0; r < 8; r++) {
        const float v = leaky(acc[r] + bb);
        out[(size_t)(row0 + r0 + r) * HID + c] = v;
        sum8 += v;
        mx8 = fmaxf(mx8, v);
    }

    // cross-half reduce (rows 0-7 with rows 8-15) and emit block partials
    __shared__ float ssum[128], smx[128];
    if (r0) { ssum[c] = sum8; smx[c] = mx8; }
    __syncthreads();
    if (!r0) {
        psum[(size_t)blockIdx.x * HID + c] = sum8 + ssum[c];
        pmax[(size_t)blockIdx.x * HID + c] = fmaxf(mx8, smx[c]);
    }
}

// ---------------------------------------------------------------------------
// Stage-2 pool: one block per graph; reduce the 32 combine-block partials.
// Coalesced (consecutive threads = consecutive cols), fixed order.
// ---------------------------------------------------------------------------
__global__ __launch_bounds__(128) void pool2_kernel(const float* __restrict__ psum,
                                                    const float* __restrict__ pmax,
                                                    float* __restrict__ g, int conv) {
    const int gr = blockIdx.x;
    const int c  = threadIdx.x;
    float s = 0.0f, m = -3.402823e38f;
    const float* ps = psum + (size_t)gr * BPGR * HID + c;
    const float* pm = pmax + (size_t)gr * BPGR * HID + c;
    #pragma unroll 8
    for (int b = 0; b < BPGR; b++) {
        s += ps[b * HID];
        m = fmaxf(m, pm[b * HID]);
    }
    float* grow = g + (size_t)gr * H6 + conv * 256;
    grow[c]       = s * (1.0f / 512.0f);
    grow[128 + c] = m;
}

// ---------------------------------------------------------------------------
template<bool BN>
__global__ __launch_bounds__(256) void lin_kernel(const float* __restrict__ gin,
                                                  const float* __restrict__ W,
                                                  const float* __restrict__ bias,
                                                  float* __restrict__ gout,
                                                  const float* __restrict__ gamma,
                                                  const float* __restrict__ beta,
                                                  const float* __restrict__ mean,
                                                  const float* __restrict__ var) {
    const int r   = blockIdx.x / 6;
    const int cc  = blockIdx.x % 6;
    const int tid = threadIdx.x;

    __shared__ float gs[H6];
    for (int k = tid; k < H6; k += 256) {
        float v = gin[(size_t)r * H6 + k];
        if (BN) v = (v - mean[k]) * (1.0f / sqrtf(var[k] + 1e-5f)) * gamma[k] + beta[k];
        gs[k] = v;
    }
    __syncthreads();

    const int c  = cc * 128 + (tid & 127);
    const int kh = tid >> 7;
    const int kb = kh * 384;
    float a0=0.f,a1=0.f,a2=0.f,a3=0.f;
    for (int k = kb; k < kb + 384; k += 4) {
        a0 += gs[k]     * W[(size_t)(k)     * H6 + c];
        a1 += gs[k + 1] * W[(size_t)(k + 1) * H6 + c];
        a2 += gs[k + 2] * W[(size_t)(k + 2) * H6 + c];
        a3 += gs[k + 3] * W[(size_t)(k + 3) * H6 + c];
    }
    __shared__ float part[256];
    part[tid] = (a0 + a1) + (a2 + a3);
    __syncthreads();
    if (kh == 0) {
        const float v = part[tid] + part[tid + 128] + bias[c];
        gout[(size_t)r * H6 + c] = leaky(v);
    }
}

__global__ void out_kernel(const float* __restrict__ gin,
                           const float* __restrict__ W,
                           const float* __restrict__ bias,
                           float* __restrict__ out) {
    const int tid = threadIdx.x;
    __shared__ float part[192];
    if (tid < 192) {
        const int q  = tid >> 2;        // 0..47
        const int r  = q / 3, c = q % 3;
        const int kq = tid & 3;
        float acc = 0.0f;
        for (int k = kq * 192; k < kq * 192 + 192; k++)
            acc += gin[(size_t)r * H6 + k] * W[(size_t)k * 3 + c];
        part[tid] = acc;
    }
    __syncthreads();
    if (tid < 48) {
        const int r = tid / 3, c = tid % 3;
        out[r * 3 + c] = part[tid*4] + part[tid*4+1] + part[tid*4+2] + part[tid*4+3] + bias[c];
    }
}

// ---------------------------------------------------------------------------
extern "C" void kernel_launch(void* const* d_in, const int* in_sizes, int n_in,
                              void* d_out, int out_size, void* d_ws, size_t ws_size,
                              hipStream_t stream) {
    const float* x        = (const float*)d_in[0];
    const float* conv1_w  = (const float*)d_in[2];
    const float* conv1_b  = (const float*)d_in[3];
    const float* conv2_w  = (const float*)d_in[4];
    const float* conv2_b  = (const float*)d_in[5];
    const float* conv3_w  = (const float*)d_in[6];
    const float* conv3_b  = (const float*)d_in[7];
    const float* bn_gamma = (const float*)d_in[8];
    const float* bn_beta  = (const float*)d_in[9];
    const float* bn_mean  = (const float*)d_in[10];
    const float* bn_var   = (const float*)d_in[11];
    const float* lin_w    = (const float*)d_in[12];
    const float* lin_b    = (const float*)d_in[13];
    const float* out_w    = (const float*)d_in[14];
    const float* out_b    = (const float*)d_in[15];

    char* ws = (char*)d_ws;
    size_t off = 0;
    auto alloc = [&](size_t bytes) {
        void* p = ws + off;
        off += (bytes + 255) & ~(size_t)255;
        return p;
    };
    int*   nbr  = (int*)  alloc((size_t)N * KNN * 4);
    float* y6a  = (float*)alloc((size_t)N * F0 * 4);
    float* y6b  = (float*)alloc((size_t)N * F0 * 4);
    float* hA   = (float*)alloc((size_t)N * HID * 4);
    float* hB   = (float*)alloc((size_t)N * HID * 4);
    float* y1   = (float*)alloc((size_t)N * HID * 4);
    float* y2   = (float*)alloc((size_t)N * HID * 4);
    float* ga   = (float*)alloc((size_t)NG * H6 * 4);
    float* gb   = (float*)alloc((size_t)NG * H6 * 4);
    float* psum = (float*)alloc((size_t)(N / RPB) * HID * 4);
    float* pmax = (float*)alloc((size_t)(N / RPB) * HID * 4);

    knn_kernel<<<N / 4, 256, 0, stream>>>(x, nbr);

    // conv1 (K=6)
    prop6<<<N / 256, 256, 0, stream>>>(x, nbr, y6a);
    prop6<<<N / 256, 256, 0, stream>>>(y6a, nbr, y6b);
    combine_kernel<6><<<N / RPB, 256, 0, stream>>>(x, y6a, y6b, conv1_w, conv1_b, hA, psum, pmax);
    pool2_kernel<<<NG, 128, 0, stream>>>(psum, pmax, ga, 0);

    // conv2 (K=128)
    prop128<<<N / 4, 128, 0, stream>>>(hA, nbr, y1);
    prop128<<<N / 4, 128, 0, stream>>>(y1, nbr, y2);
    combine_kernel<128><<<N / RPB, 256, 0, stream>>>(hA, y1, y2, conv2_w, conv2_b, hB, psum, pmax);
    pool2_kernel<<<NG, 128, 0, stream>>>(psum, pmax, ga, 1);

    // conv3 (K=128)
    prop128<<<N / 4, 128, 0, stream>>>(hB, nbr, y1);
    prop128<<<N / 4, 128, 0, stream>>>(y1, nbr, y2);
    combine_kernel<128><<<N / RPB, 256, 0, stream>>>(hB, y1, y2, conv3_w, conv3_b, hA, psum, pmax);
    pool2_kernel<<<NG, 128, 0, stream>>>(psum, pmax, ga, 2);

    // head (BN fused into first layer's staging)
    lin_kernel<true ><<<96, 256, 0, stream>>>(ga, lin_w + 0 * H6 * H6, lin_b + 0 * H6, gb,
                                              bn_gamma, bn_beta, bn_mean, bn_var);
    lin_kernel<false><<<96, 256, 0, stream>>>(gb, lin_w + 1 * H6 * H6, lin_b + 1 * H6, ga,
                                              nullptr, nullptr, nullptr, nullptr);
    lin_kernel<false><<<96, 256, 0, stream>>>(ga, lin_w + 2 * H6 * H6, lin_b + 2 * H6, gb,
                                              nullptr, nullptr, nullptr, nullptr);
    lin_kernel<false><<<96, 256, 0, stream>>>(gb, lin_w + 3 * H6 * H6, lin_b + 3 * H6, ga,
                                              nullptr, nullptr, nullptr, nullptr);
    lin_kernel<false><<<96, 256, 0, stream>>>(ga, lin_w + 4 * H6 * H6, lin_b + 4 * H6, gb,
                                              nullptr, nullptr, nullptr, nullptr);
    out_kernel<<<1, 256, 0, stream>>>(gb, out_w, out_b, (float*)d_out);
}